// Round 2
// baseline (1174.514 us; speedup 1.0000x reference)
//
#include <hip/hip_runtime.h>
#include <cstdint>
#include <cstddef>

#define TT 64
#define BB 256
#define FEAT 924
#define HH 512
#define NC 151
#define ED 100
#define KIN 1024      // FEAT + ED
#define SIXH 3072
#define FIVEH 2560
#define MROWS (TT * BB)   // 16384

typedef __bf16 bf16_t;
typedef __bf16 bf16x8 __attribute__((ext_vector_type(8)));
typedef float f32x4 __attribute__((ext_vector_type(4)));

typedef __attribute__((address_space(1))) const unsigned int* gptr_t;
typedef __attribute__((address_space(3))) unsigned int* lptr_t;

__device__ __forceinline__ void gload16(const void* g, void* l) {
  __builtin_amdgcn_global_load_lds((gptr_t)g, (lptr_t)l, 16, 0, 0);
}

__device__ __forceinline__ f32x4 mfma16(bf16x8 a, bf16x8 b, f32x4 c) {
  return __builtin_amdgcn_mfma_f32_16x16x32_bf16(a, b, c, 0, 0, 0);
}

__device__ __forceinline__ float fsig(float x) {
  return 1.f / (1.f + __expf(-x));
}
__device__ __forceinline__ float ftanh_(float x) {
  return 1.f - 2.f / (1.f + __expf(2.f * x));
}

// ---------------- conversions ----------------
__global__ void k_f2b(const float* __restrict__ in, bf16_t* __restrict__ out, int n) {
  int i = blockIdx.x * 256 + threadIdx.x;
  int stride = gridDim.x * 256;
  for (; i < n; i += stride) out[i] = (bf16_t)in[i];
}

// Wo (151,512) -> zero-padded (256,512) bf16
__global__ void k_wopad(const float* __restrict__ wo, bf16_t* __restrict__ out) {
  int i = blockIdx.x * 256 + threadIdx.x;   // 256*512 = 131072 total
  int r = i >> 9, k = i & 511;
  out[i] = (r < NC) ? (bf16_t)wo[r * HH + k] : (bf16_t)0.f;
}

// TI[row][0..923] = x[row], TI[row][924..1023] = embed[labels[row]]
__global__ void k_gather(const float* __restrict__ x, const int* __restrict__ lab,
                         const float* __restrict__ emb, bf16_t* __restrict__ ti) {
  int row = blockIdx.x;
  int t = threadIdx.x;
  int lb = lab[row];
  const float* xr = x + (size_t)row * FEAT;
  bf16_t* tr = ti + (size_t)row * KIN;
#pragma unroll
  for (int e = 0; e < 4; ++e) {
    int col = t + e * 256;
    float v = (col < FEAT) ? xr[col] : emb[lb * ED + (col - FEAT)];
    tr[col] = (bf16_t)v;
  }
}

// ---------------- generic C = A(M,K) * Bm(N,K)^T + bias, bf16 MFMA ----------------
// 128x128 tile, BK=64, 4 waves; XOR-swizzled LDS (swizzle on global src AND ds_read).
template <typename CT>
__global__ __launch_bounds__(256)
void k_gemm(const bf16_t* __restrict__ A, const bf16_t* __restrict__ Bm,
            const float* __restrict__ bias, CT* __restrict__ C,
            int M, int N, int K, int ldc, int nstore) {
  __shared__ __align__(16) bf16_t As[128 * 64];
  __shared__ __align__(16) bf16_t Bs[128 * 64];
  const int tid = threadIdx.x;
  const int l = tid & 63;
  const int w = tid >> 6;
  const int wr = w >> 1, wc = w & 1;
  const int m0 = blockIdx.y * 128, n0 = blockIdx.x * 128;
  const int l15 = l & 15, lq = l >> 4;

  f32x4 acc[4][4] = {};

  for (int k0 = 0; k0 < K; k0 += 64) {
#pragma unroll
    for (int q = 0; q < 4; ++q) {
      int rig = q * 32 + w * 8 + (l >> 3);
      int kc = (l & 7) ^ (rig & 7);   // source pre-swizzle (both-sides rule #21)
      gload16(A + (size_t)(m0 + rig) * K + k0 + kc * 8, As + q * 2048 + w * 512);
      gload16(Bm + (size_t)(n0 + rig) * K + k0 + kc * 8, Bs + q * 2048 + w * 512);
    }
    __syncthreads();   // compiler drains vmcnt(0) before barrier -> staging complete
#pragma unroll
    for (int ks = 0; ks < 2; ++ks) {
      bf16x8 af[4], bf[4];
#pragma unroll
      for (int m = 0; m < 4; ++m) {
        int row = wr * 64 + m * 16 + l15;
        int kcs = (ks * 4 + lq) ^ (row & 7);
        af[m] = *(const bf16x8*)(As + row * 64 + kcs * 8);
      }
#pragma unroll
      for (int n = 0; n < 4; ++n) {
        int row = wc * 64 + n * 16 + l15;
        int kcs = (ks * 4 + lq) ^ (row & 7);
        bf[n] = *(const bf16x8*)(Bs + row * 64 + kcs * 8);
      }
#pragma unroll
      for (int m = 0; m < 4; ++m)
#pragma unroll
        for (int n = 0; n < 4; ++n)
          acc[m][n] = mfma16(af[m], bf[n], acc[m][n]);
    }
    __syncthreads();
  }

#pragma unroll
  for (int n = 0; n < 4; ++n) {
    int ccol = n0 + wc * 64 + n * 16 + l15;
    if (ccol >= nstore) continue;
    float bv = bias[ccol];
#pragma unroll
    for (int m = 0; m < 4; ++m) {
      int crow = m0 + wr * 64 + m * 16 + lq * 4;
#pragma unroll
      for (int j = 0; j < 4; ++j)
        C[(size_t)(crow + j) * ldc + ccol] = (CT)(acc[m][n][j] + bv);
    }
  }
}

// ---------------- one recurrent timestep ----------------
// grid (B/32, H/32), 64 threads (1 wave). WG owns h-tile (32 b-rows x 32 j-cols):
// 5 gate GEMMs (K=512) + fused gate elementwise. Counted-vmcnt double-buffered staging.
__global__ __launch_bounds__(64)
void k_step(const bf16_t* __restrict__ hprev, const bf16_t* __restrict__ Wsb,
            const float* __restrict__ bs, const float* __restrict__ pi_t,
            const float* __restrict__ mask, float* __restrict__ c,
            bf16_t* __restrict__ hout) {
  __shared__ __align__(16) bf16_t Ah[2][32 * 64];
  __shared__ __align__(16) bf16_t Bw[2][5 * 32 * 64];
  const int l = threadIdx.x;
  const int b0 = blockIdx.x * 32, j0 = blockIdx.y * 32;
  const int l15 = l & 15, lq = l >> 4;
  const int rig0 = l >> 3;
  const int kc7 = l & 7;

  f32x4 acc[5][2][2] = {};

  auto stage = [&](int buf, int k0) {
#pragma unroll
    for (int q = 0; q < 4; ++q) {
      int r = q * 8 + rig0;
      int kc = kc7 ^ (r & 7);
      gload16(hprev + (size_t)(b0 + r) * HH + k0 + kc * 8, &Ah[buf][q * 512]);
    }
#pragma unroll
    for (int g = 0; g < 5; ++g)
#pragma unroll
      for (int q = 0; q < 4; ++q) {
        int r = q * 8 + rig0;
        int kc = kc7 ^ (r & 7);
        gload16(Wsb + (size_t)(g * HH + j0 + r) * HH + k0 + kc * 8,
                &Bw[buf][g * 2048 + q * 512]);
      }
  };

  stage(0, 0);
  int buf = 0;
  for (int ck = 0; ck < 8; ++ck) {
    if (ck < 7) {
      stage(buf ^ 1, (ck + 1) * 64);                    // 24 loads in flight ahead
      asm volatile("s_waitcnt vmcnt(24)" ::: "memory"); // current chunk landed
    } else {
      asm volatile("s_waitcnt vmcnt(0)" ::: "memory");
    }
#pragma unroll
    for (int ks = 0; ks < 2; ++ks) {
      bf16x8 af[2], bfr[5][2];
#pragma unroll
      for (int m = 0; m < 2; ++m) {
        int row = m * 16 + l15;
        int kcs = (ks * 4 + lq) ^ (row & 7);
        af[m] = *(const bf16x8*)(&Ah[buf][row * 64 + kcs * 8]);
      }
#pragma unroll
      for (int g = 0; g < 5; ++g)
#pragma unroll
        for (int n = 0; n < 2; ++n) {
          int row = n * 16 + l15;
          int kcs = (ks * 4 + lq) ^ (row & 7);
          bfr[g][n] = *(const bf16x8*)(&Bw[buf][g * 2048 + row * 64 + kcs * 8]);
        }
#pragma unroll
      for (int g = 0; g < 5; ++g)
#pragma unroll
        for (int m = 0; m < 2; ++m)
#pragma unroll
          for (int n = 0; n < 2; ++n)
            acc[g][m][n] = mfma16(af[m], bfr[g][n], acc[g][m][n]);
    }
    buf ^= 1;
  }

  // fused gates / state update / highway / dropout mask
#pragma unroll
  for (int m = 0; m < 2; ++m)
#pragma unroll
    for (int n = 0; n < 2; ++n)
#pragma unroll
      for (int r = 0; r < 4; ++r) {
        int b = b0 + m * 16 + lq * 4 + r;
        int j = j0 + n * 16 + l15;
        size_t pib = (size_t)b * SIXH + j;
        float p0 = pi_t[pib];
        float p1 = pi_t[pib + HH];
        float p2 = pi_t[pib + 2 * HH];
        float p3 = pi_t[pib + 3 * HH];
        float p4 = pi_t[pib + 4 * HH];
        float p5 = pi_t[pib + 5 * HH];
        float ig = fsig(p0 + acc[0][m][n][r] + bs[j]);
        float fg = fsig(p1 + acc[1][m][n][r] + bs[HH + j]);
        float mi = ftanh_(p2 + acc[2][m][n][r] + bs[2 * HH + j]);
        float og = fsig(p3 + acc[3][m][n][r] + bs[3 * HH + j]);
        float hg = fsig(p4 + acc[4][m][n][r] + bs[4 * HH + j]);
        size_t cix = (size_t)b * HH + j;
        float cn = ig * mi + fg * c[cix];
        c[cix] = cn;
        float o = og * ftanh_(cn);
        o = hg * o + (1.f - hg) * p5;
        o *= mask[cix];
        hout[cix] = (bf16_t)o;
      }
}

// ---------------- launcher ----------------
extern "C" void kernel_launch(void* const* d_in, const int* in_sizes, int n_in,
                              void* d_out, int out_size, void* d_ws, size_t ws_size,
                              hipStream_t stream) {
  const float* x    = (const float*)d_in[0];
  const int*   lab  = (const int*)d_in[1];
  const float* emb  = (const float*)d_in[2];
  const float* Wi   = (const float*)d_in[3];
  const float* bi   = (const float*)d_in[4];
  const float* Ws   = (const float*)d_in[5];
  const float* bs   = (const float*)d_in[6];
  const float* Wo   = (const float*)d_in[7];
  const float* bo   = (const float*)d_in[8];
  const float* mask = (const float*)d_in[9];
  float* out = (float*)d_out;

  char* w = (char*)d_ws;
  size_t off = 0;
  auto take = [&](size_t bytes) {
    void* p = w + off;
    off += (bytes + 255) & ~(size_t)255;
    return p;
  };

  bf16_t* TI   = (bf16_t*)take((size_t)MROWS * KIN * 2);
  bf16_t* Wib  = (bf16_t*)take((size_t)SIXH * KIN * 2);
  bf16_t* Wsb  = (bf16_t*)take((size_t)FIVEH * HH * 2);
  bf16_t* Wob  = (bf16_t*)take((size_t)256 * HH * 2);
  bf16_t* Hs   = (bf16_t*)take((size_t)(TT + 1) * BB * HH * 2);  // slot 0 = h0 = 0
  float*  cbuf = (float*)take((size_t)BB * HH * 4);
  float*  pi   = (float*)(w + off);
  size_t avail = (ws_size > off) ? (ws_size - off) : 0;

  // pick the largest time-chunk for fp32 pi that fits the workspace
  int TCH = 0;
  const int cand[6] = {TT, 16, 8, 4, 2, 1};
  for (int i = 0; i < 6; ++i) {
    if (avail >= (size_t)cand[i] * BB * SIXH * 4) { TCH = cand[i]; break; }
  }
  if (TCH == 0) {
    // workspace too small for any layout: emit zeros as a diagnostic signal
    hipMemsetAsync(d_out, 0, (size_t)out_size * 4, stream);
    return;
  }

  // weight conversions + input gather/concat
  k_f2b<<<dim3(1024), dim3(256), 0, stream>>>(Wi, Wib, SIXH * KIN);
  k_f2b<<<dim3(512), dim3(256), 0, stream>>>(Ws, Wsb, FIVEH * HH);
  k_wopad<<<dim3(512), dim3(256), 0, stream>>>(Wo, Wob);
  k_gather<<<dim3(MROWS), dim3(256), 0, stream>>>(x, lab, emb, TI);
  hipMemsetAsync(Hs, 0, (size_t)BB * HH * 2, stream);
  hipMemsetAsync(cbuf, 0, (size_t)BB * HH * 4, stream);

  // input projection (chunked over time) + recurrence
  for (int c0 = 0; c0 < TT; c0 += TCH) {
    int mrows = TCH * BB;
    k_gemm<float><<<dim3(SIXH / 128, mrows / 128), dim3(256), 0, stream>>>(
        TI + (size_t)c0 * BB * KIN, Wib, bi, pi, mrows, SIXH, KIN, SIXH, SIXH);
    for (int t = c0; t < c0 + TCH; ++t)
      k_step<<<dim3(BB / 32, HH / 32), dim3(64), 0, stream>>>(
          Hs + (size_t)t * BB * HH, Wsb, bs, pi + (size_t)(t - c0) * BB * SIXH,
          mask, cbuf, Hs + (size_t)(t + 1) * BB * HH);
  }

  // batched output projection: pred = h @ Wo^T + bo  (Wo zero-padded to 256 rows)
  k_gemm<float><<<dim3(2, MROWS / 128), dim3(256), 0, stream>>>(
      Hs + (size_t)BB * HH, Wob, bo, out, MROWS, 256, HH, NC, NC);
}

// Round 3
// 1092.493 us; speedup vs baseline: 1.0751x; 1.0751x over previous
//
#include <hip/hip_runtime.h>
#include <cstdint>
#include <cstddef>

#define TT 64
#define BB 256
#define FEAT 924
#define HH 512
#define NC 151
#define ED 100
#define KIN 1024      // FEAT + ED
#define SIXH 3072
#define FIVEH 2560
#define MROWS (TT * BB)   // 16384
#define RLDS 114688       // 80KB Wl + 32KB Ah

typedef __bf16 bf16_t;
typedef __bf16 bf16x8 __attribute__((ext_vector_type(8)));
typedef float f32x4 __attribute__((ext_vector_type(4)));

typedef __attribute__((address_space(1))) const unsigned int* gptr_t;
typedef __attribute__((address_space(3))) unsigned int* lptr_t;

__device__ __forceinline__ void gload16(const void* g, void* l) {
  __builtin_amdgcn_global_load_lds((gptr_t)g, (lptr_t)l, 16, 0, 0);
}

__device__ __forceinline__ f32x4 mfma16(bf16x8 a, bf16x8 b, f32x4 c) {
  return __builtin_amdgcn_mfma_f32_16x16x32_bf16(a, b, c, 0, 0, 0);
}

__device__ __forceinline__ float fsig(float x) {
  return 1.f / (1.f + __expf(-x));
}
__device__ __forceinline__ float ftanh_(float x) {
  return 1.f - 2.f / (1.f + __expf(2.f * x));
}

// ---------------- conversions ----------------
__global__ void k_f2b(const float* __restrict__ in, bf16_t* __restrict__ out, int n) {
  int i = blockIdx.x * 256 + threadIdx.x;
  int stride = gridDim.x * 256;
  for (; i < n; i += stride) out[i] = (bf16_t)in[i];
}

// Wo (151,512) -> zero-padded (256,512) bf16
__global__ void k_wopad(const float* __restrict__ wo, bf16_t* __restrict__ out) {
  int i = blockIdx.x * 256 + threadIdx.x;   // 256*512 = 131072 total
  int r = i >> 9, k = i & 511;
  out[i] = (r < NC) ? (bf16_t)wo[r * HH + k] : (bf16_t)0.f;
}

// TI[row][0..923] = x[row], TI[row][924..1023] = embed[labels[row]]
__global__ void k_gather(const float* __restrict__ x, const int* __restrict__ lab,
                         const float* __restrict__ emb, bf16_t* __restrict__ ti) {
  int row = blockIdx.x;
  int t = threadIdx.x;
  int lb = lab[row];
  const float* xr = x + (size_t)row * FEAT;
  bf16_t* tr = ti + (size_t)row * KIN;
#pragma unroll
  for (int e = 0; e < 4; ++e) {
    int col = t + e * 256;
    float v = (col < FEAT) ? xr[col] : emb[lb * ED + (col - FEAT)];
    tr[col] = (bf16_t)v;
  }
}

// ---------------- generic C = A(M,K) * Bm(N,K)^T + bias, bf16 MFMA ----------------
// 128x128 tile, BK=64, 4 waves; XOR-swizzled LDS (swizzle on global src AND ds_read).
template <typename CT>
__global__ __launch_bounds__(256)
void k_gemm(const bf16_t* __restrict__ A, const bf16_t* __restrict__ Bm,
            const float* __restrict__ bias, CT* __restrict__ C,
            int M, int N, int K, int ldc, int nstore) {
  __shared__ __align__(16) bf16_t As[128 * 64];
  __shared__ __align__(16) bf16_t Bs[128 * 64];
  const int tid = threadIdx.x;
  const int l = tid & 63;
  const int w = tid >> 6;
  const int wr = w >> 1, wc = w & 1;
  const int m0 = blockIdx.y * 128, n0 = blockIdx.x * 128;
  const int l15 = l & 15, lq = l >> 4;

  f32x4 acc[4][4] = {};

  for (int k0 = 0; k0 < K; k0 += 64) {
#pragma unroll
    for (int q = 0; q < 4; ++q) {
      int rig = q * 32 + w * 8 + (l >> 3);
      int kc = (l & 7) ^ (rig & 7);   // source pre-swizzle (both-sides rule #21)
      gload16(A + (size_t)(m0 + rig) * K + k0 + kc * 8, As + q * 2048 + w * 512);
      gload16(Bm + (size_t)(n0 + rig) * K + k0 + kc * 8, Bs + q * 2048 + w * 512);
    }
    __syncthreads();
#pragma unroll
    for (int ks = 0; ks < 2; ++ks) {
      bf16x8 af[4], bf[4];
#pragma unroll
      for (int m = 0; m < 4; ++m) {
        int row = wr * 64 + m * 16 + l15;
        int kcs = (ks * 4 + lq) ^ (row & 7);
        af[m] = *(const bf16x8*)(As + row * 64 + kcs * 8);
      }
#pragma unroll
      for (int n = 0; n < 4; ++n) {
        int row = wc * 64 + n * 16 + l15;
        int kcs = (ks * 4 + lq) ^ (row & 7);
        bf[n] = *(const bf16x8*)(Bs + row * 64 + kcs * 8);
      }
#pragma unroll
      for (int m = 0; m < 4; ++m)
#pragma unroll
        for (int n = 0; n < 4; ++n)
          acc[m][n] = mfma16(af[m], bf[n], acc[m][n]);
    }
    __syncthreads();
  }

#pragma unroll
  for (int n = 0; n < 4; ++n) {
    int ccol = n0 + wc * 64 + n * 16 + l15;
    if (ccol >= nstore) continue;
    float bv = bias[ccol];
#pragma unroll
    for (int m = 0; m < 4; ++m) {
      int crow = m0 + wr * 64 + m * 16 + lq * 4;
#pragma unroll
      for (int j = 0; j < 4; ++j)
        C[(size_t)(crow + j) * ldc + ccol] = (CT)(acc[m][n][j] + bv);
    }
  }
}

// ---------------- persistent recurrence: all 64 steps in one launch ----------------
// grid (8, 32) = 256 WGs x 64 thr, 1 WG/CU (LDS-limited). WG owns b-tile 32 x j-tile 16.
// Ws slice lives in LDS all 64 steps; c and mask live in registers. Per-step sync is a
// 32-wide atomic barrier among the WGs sharing a b-tile (batch rows are independent).
template <typename PIT>
__global__ __launch_bounds__(64)
void k_recur(const bf16_t* __restrict__ Wsb, const float* __restrict__ bs,
             const PIT* __restrict__ pi, const float* __restrict__ mask,
             bf16_t* __restrict__ Hs, unsigned* __restrict__ ctr) {
  extern __shared__ __align__(16) char smem[];
  bf16_t* Wl = (bf16_t*)smem;              // [5][16][512] swizzled, persistent
  bf16_t* Ah = (bf16_t*)(smem + 81920);    // [32][512] swizzled, per step
  const int l = threadIdx.x;
  const int l15 = l & 15, lq = l >> 4;
  const int key = l15 & 7;
  const int bq = blockIdx.x, jq = blockIdx.y;
  const int b0 = bq * 32, j0 = jq * 16;
  const int j = j0 + l15;
  unsigned* myctr = ctr + bq * 64;         // 256B apart per group

  // per-lane pre-swizzled source chunk offsets (elements), key = row&7
  int swz8[8];
#pragma unroll
  for (int k = 0; k < 8; ++k) swz8[k] = (((l & ~7) | ((l & 7) ^ k)) << 3);

  // one-time: stage Ws gate rows into LDS (swizzled source -> linear dest)
#pragma unroll
  for (int g = 0; g < 5; ++g)
#pragma unroll
    for (int jl = 0; jl < 16; ++jl)
      gload16(Wsb + (size_t)(g * HH + j0 + jl) * HH + swz8[jl & 7],
              Wl + (g * 16 + jl) * 512);

  float bsr[5];
#pragma unroll
  for (int g = 0; g < 5; ++g) bsr[g] = bs[g * HH + j];
  float mreg[8], creg[8] = {0.f, 0.f, 0.f, 0.f, 0.f, 0.f, 0.f, 0.f};
#pragma unroll
  for (int m = 0; m < 2; ++m)
#pragma unroll
    for (int r = 0; r < 4; ++r)
      mreg[m * 4 + r] = mask[(size_t)(b0 + m * 16 + lq * 4 + r) * HH + j];

  for (int t = 0; t < TT; ++t) {
    // stage h_t slice [32][512] (Hs[0] is zeroed)
    const bf16_t* hrow = Hs + (size_t)t * BB * HH + (size_t)b0 * HH;
#pragma unroll
    for (int r = 0; r < 32; ++r)
      gload16(hrow + r * HH + swz8[r & 7], Ah + r * 512);

    // early-issue pi loads; latency overlaps the Ah staging wait
    const PIT* pit = pi + (size_t)t * BB * SIXH;
    float pv[2][4][6];
#pragma unroll
    for (int m = 0; m < 2; ++m)
#pragma unroll
      for (int r = 0; r < 4; ++r) {
        const PIT* prow = pit + (size_t)(b0 + m * 16 + lq * 4 + r) * SIXH + j;
#pragma unroll
        for (int g = 0; g < 6; ++g) pv[m][r][g] = (float)prow[g * HH];
      }

    asm volatile("s_waitcnt vmcnt(0)" ::: "memory");   // Ah (and Wl at t=0) landed

    f32x4 acc[5][2] = {};
#pragma unroll
    for (int ks = 0; ks < 16; ++ks) {
      int slot = ((ks >> 1) << 3) | (((ks & 1) * 4 + lq) ^ key);
      bf16x8 a0 = *(const bf16x8*)(Ah + l15 * 512 + slot * 8);
      bf16x8 a1 = *(const bf16x8*)(Ah + (16 + l15) * 512 + slot * 8);
#pragma unroll
      for (int g = 0; g < 5; ++g) {
        bf16x8 bb = *(const bf16x8*)(Wl + (g * 16 + l15) * 512 + slot * 8);
        acc[g][0] = mfma16(a0, bb, acc[g][0]);
        acc[g][1] = mfma16(a1, bb, acc[g][1]);
      }
    }

    // fused gates / state / highway / dropout; h store
    bf16_t* hnext = Hs + (size_t)(t + 1) * BB * HH;
#pragma unroll
    for (int m = 0; m < 2; ++m)
#pragma unroll
      for (int r = 0; r < 4; ++r) {
        int e = m * 4 + r;
        int b = b0 + m * 16 + lq * 4 + r;
        float ig = fsig(pv[m][r][0] + acc[0][m][r] + bsr[0]);
        float fg = fsig(pv[m][r][1] + acc[1][m][r] + bsr[1]);
        float mi = ftanh_(pv[m][r][2] + acc[2][m][r] + bsr[2]);
        float og = fsig(pv[m][r][3] + acc[3][m][r] + bsr[3]);
        float hg = fsig(pv[m][r][4] + acc[4][m][r] + bsr[4]);
        float cn = ig * mi + fg * creg[e];
        creg[e] = cn;
        float o = og * ftanh_(cn);
        o = hg * o + (1.f - hg) * pv[m][r][5];
        o *= mreg[e];
        hnext[(size_t)b * HH + j] = (bf16_t)o;
      }

    // per-b-group barrier (32 WGs), monotone counter, cross-XCD fences
    if (t < TT - 1) {
      asm volatile("s_waitcnt vmcnt(0) lgkmcnt(0)" ::: "memory");
      __builtin_amdgcn_fence(__ATOMIC_RELEASE, "agent");
      if (l == 0) {
        __hip_atomic_fetch_add(myctr, 1u, __ATOMIC_RELAXED, __HIP_MEMORY_SCOPE_AGENT);
        unsigned tgt = 32u * (unsigned)(t + 1);
        while (__hip_atomic_load(myctr, __ATOMIC_RELAXED, __HIP_MEMORY_SCOPE_AGENT) < tgt)
          __builtin_amdgcn_s_sleep(2);
      }
      __builtin_amdgcn_fence(__ATOMIC_ACQUIRE, "agent");
    }
  }
}

// ---------------- launcher ----------------
extern "C" void kernel_launch(void* const* d_in, const int* in_sizes, int n_in,
                              void* d_out, int out_size, void* d_ws, size_t ws_size,
                              hipStream_t stream) {
  const float* x    = (const float*)d_in[0];
  const int*   lab  = (const int*)d_in[1];
  const float* emb  = (const float*)d_in[2];
  const float* Wi   = (const float*)d_in[3];
  const float* bi   = (const float*)d_in[4];
  const float* Ws   = (const float*)d_in[5];
  const float* bs   = (const float*)d_in[6];
  const float* Wo   = (const float*)d_in[7];
  const float* bo   = (const float*)d_in[8];
  const float* mask = (const float*)d_in[9];
  float* out = (float*)d_out;

  char* w = (char*)d_ws;
  size_t off = 0;
  auto take = [&](size_t bytes) {
    void* p = w + off;
    off += (bytes + 255) & ~(size_t)255;
    return p;
  };

  bf16_t*   TI   = (bf16_t*)take((size_t)MROWS * KIN * 2);
  bf16_t*   Wib  = (bf16_t*)take((size_t)SIXH * KIN * 2);
  bf16_t*   Wsb  = (bf16_t*)take((size_t)FIVEH * HH * 2);
  bf16_t*   Wob  = (bf16_t*)take((size_t)256 * HH * 2);
  bf16_t*   Hs   = (bf16_t*)take((size_t)(TT + 1) * BB * HH * 2);  // slot 0 = h0 = 0
  unsigned* ctrs = (unsigned*)take(8 * 64 * sizeof(unsigned));
  void* piPtr = w + off;
  size_t avail = (ws_size > off) ? (ws_size - off) : 0;

  bool pifp32 = avail >= (size_t)MROWS * SIXH * 4;
  bool pibf16 = !pifp32 && avail >= (size_t)MROWS * SIXH * 2;
  if (!pifp32 && !pibf16) {
    hipMemsetAsync(d_out, 0, (size_t)out_size * 4, stream);  // diagnostic: ws too small
    return;
  }

  // weight conversions + input gather/concat + state init
  k_f2b<<<dim3(1024), dim3(256), 0, stream>>>(Wi, Wib, SIXH * KIN);
  k_f2b<<<dim3(512), dim3(256), 0, stream>>>(Ws, Wsb, FIVEH * HH);
  k_wopad<<<dim3(512), dim3(256), 0, stream>>>(Wo, Wob);
  k_gather<<<dim3(MROWS), dim3(256), 0, stream>>>(x, lab, emb, TI);
  hipMemsetAsync(Hs, 0, (size_t)BB * HH * 2, stream);
  hipMemsetAsync(ctrs, 0, 8 * 64 * sizeof(unsigned), stream);

  dim3 rg(8, 32), rb(64);
  if (pifp32) {
    float* pi = (float*)piPtr;
    k_gemm<float><<<dim3(SIXH / 128, MROWS / 128), dim3(256), 0, stream>>>(
        TI, Wib, bi, pi, MROWS, SIXH, KIN, SIXH, SIXH);
    const float* piC = pi;
    hipFuncSetAttribute((const void*)k_recur<float>,
                        hipFuncAttributeMaxDynamicSharedMemorySize, RLDS);
    void* args[6] = {&Wsb, &bs, &piC, &mask, &Hs, &ctrs};
    hipError_t e = hipLaunchCooperativeKernel((void*)k_recur<float>, rg, rb, args,
                                              RLDS, stream);
    if (e != hipSuccess)
      k_recur<float><<<rg, rb, RLDS, stream>>>(Wsb, bs, piC, mask, Hs, ctrs);
  } else {
    bf16_t* pi = (bf16_t*)piPtr;
    k_gemm<bf16_t><<<dim3(SIXH / 128, MROWS / 128), dim3(256), 0, stream>>>(
        TI, Wib, bi, pi, MROWS, SIXH, KIN, SIXH, SIXH);
    const bf16_t* piC = pi;
    hipFuncSetAttribute((const void*)k_recur<bf16_t>,
                        hipFuncAttributeMaxDynamicSharedMemorySize, RLDS);
    void* args[6] = {&Wsb, &bs, &piC, &mask, &Hs, &ctrs};
    hipError_t e = hipLaunchCooperativeKernel((void*)k_recur<bf16_t>, rg, rb, args,
                                              RLDS, stream);
    if (e != hipSuccess)
      k_recur<bf16_t><<<rg, rb, RLDS, stream>>>(Wsb, bs, piC, mask, Hs, ctrs);
  }

  // batched output projection: pred = h @ Wo^T + bo  (Wo zero-padded to 256 rows)
  k_gemm<float><<<dim3(2, MROWS / 128), dim3(256), 0, stream>>>(
      Hs + (size_t)BB * HH, Wob, bo, out, MROWS, 256, HH, NC, NC);
}

// Round 4
// 654.222 us; speedup vs baseline: 1.7953x; 1.6699x over previous
//
#include <hip/hip_runtime.h>
#include <cstdint>
#include <cstddef>

#define TT 64
#define BB 256
#define FEAT 924
#define HH 512
#define NC 151
#define ED 100
#define KIN 1024      // FEAT + ED
#define SIXH 3072
#define FIVEH 2560
#define MROWS (TT * BB)   // 16384
#define RLDS 81920        // Wl: 5 gates x 16 kk x 64 lanes x 16B

typedef __bf16 bf16_t;
typedef __bf16 bf16x8 __attribute__((ext_vector_type(8)));
typedef float f32x4 __attribute__((ext_vector_type(4)));

typedef __attribute__((address_space(1))) const unsigned int* gptr_t;
typedef __attribute__((address_space(3))) unsigned int* lptr_t;

__device__ __forceinline__ void gload16(const void* g, void* l) {
  __builtin_amdgcn_global_load_lds((gptr_t)g, (lptr_t)l, 16, 0, 0);
}

__device__ __forceinline__ f32x4 mfma16(bf16x8 a, bf16x8 b, f32x4 c) {
  return __builtin_amdgcn_mfma_f32_16x16x32_bf16(a, b, c, 0, 0, 0);
}

__device__ __forceinline__ float fsig(float x) {
  return 1.f / (1.f + __expf(-x));
}
__device__ __forceinline__ float ftanh_(float x) {
  return 1.f - 2.f / (1.f + __expf(2.f * x));
}

// ---------------- conversions ----------------
__global__ void k_f2b(const float* __restrict__ in, bf16_t* __restrict__ out, int n) {
  int i = blockIdx.x * 256 + threadIdx.x;
  int stride = gridDim.x * 256;
  for (; i < n; i += stride) out[i] = (bf16_t)in[i];
}

// Wo (151,512) -> zero-padded (256,512) bf16
__global__ void k_wopad(const float* __restrict__ wo, bf16_t* __restrict__ out) {
  int i = blockIdx.x * 256 + threadIdx.x;   // 256*512 = 131072 total
  int r = i >> 9, k = i & 511;
  out[i] = (r < NC) ? (bf16_t)wo[r * HH + k] : (bf16_t)0.f;
}

// TI[row][0..923] = x[row], TI[row][924..1023] = embed[labels[row]]
__global__ void k_gather(const float* __restrict__ x, const int* __restrict__ lab,
                         const float* __restrict__ emb, bf16_t* __restrict__ ti) {
  int row = blockIdx.x;
  int t = threadIdx.x;
  int lb = lab[row];
  const float* xr = x + (size_t)row * FEAT;
  bf16_t* tr = ti + (size_t)row * KIN;
#pragma unroll
  for (int e = 0; e < 4; ++e) {
    int col = t + e * 256;
    float v = (col < FEAT) ? xr[col] : emb[lb * ED + (col - FEAT)];
    tr[col] = (bf16_t)v;
  }
}

// ---------------- generic C = A(M,K) * Bm(N,K)^T + bias, bf16 MFMA ----------------
// 128x128 tile, BK=64, 4 waves; XOR-swizzled LDS (swizzle on global src AND ds_read).
template <typename CT>
__global__ __launch_bounds__(256)
void k_gemm(const bf16_t* __restrict__ A, const bf16_t* __restrict__ Bm,
            const float* __restrict__ bias, CT* __restrict__ C,
            int M, int N, int K, int ldc, int nstore) {
  __shared__ __align__(16) bf16_t As[128 * 64];
  __shared__ __align__(16) bf16_t Bs[128 * 64];
  const int tid = threadIdx.x;
  const int l = tid & 63;
  const int w = tid >> 6;
  const int wr = w >> 1, wc = w & 1;
  const int m0 = blockIdx.y * 128, n0 = blockIdx.x * 128;
  const int l15 = l & 15, lq = l >> 4;

  f32x4 acc[4][4] = {};

  for (int k0 = 0; k0 < K; k0 += 64) {
#pragma unroll
    for (int q = 0; q < 4; ++q) {
      int rig = q * 32 + w * 8 + (l >> 3);
      int kc = (l & 7) ^ (rig & 7);   // source pre-swizzle (both-sides rule #21)
      gload16(A + (size_t)(m0 + rig) * K + k0 + kc * 8, As + q * 2048 + w * 512);
      gload16(Bm + (size_t)(n0 + rig) * K + k0 + kc * 8, Bs + q * 2048 + w * 512);
    }
    __syncthreads();
#pragma unroll
    for (int ks = 0; ks < 2; ++ks) {
      bf16x8 af[4], bf[4];
#pragma unroll
      for (int m = 0; m < 4; ++m) {
        int row = wr * 64 + m * 16 + l15;
        int kcs = (ks * 4 + lq) ^ (row & 7);
        af[m] = *(const bf16x8*)(As + row * 64 + kcs * 8);
      }
#pragma unroll
      for (int n = 0; n < 4; ++n) {
        int row = wc * 64 + n * 16 + l15;
        int kcs = (ks * 4 + lq) ^ (row & 7);
        bf[n] = *(const bf16x8*)(Bs + row * 64 + kcs * 8);
      }
#pragma unroll
      for (int m = 0; m < 4; ++m)
#pragma unroll
        for (int n = 0; n < 4; ++n)
          acc[m][n] = mfma16(af[m], bf[n], acc[m][n]);
    }
    __syncthreads();
  }

#pragma unroll
  for (int n = 0; n < 4; ++n) {
    int ccol = n0 + wc * 64 + n * 16 + l15;
    if (ccol >= nstore) continue;
    float bv = bias[ccol];
#pragma unroll
    for (int m = 0; m < 4; ++m) {
      int crow = m0 + wr * 64 + m * 16 + lq * 4;
#pragma unroll
      for (int j = 0; j < 4; ++j)
        C[(size_t)(crow + j) * ldc + ccol] = (CT)(acc[m][n][j] + bv);
    }
  }
}

// ---------------- persistent recurrence: all 64 steps in one launch ----------------
// grid (8, 32) x 128 thr (2 waves). WG owns b-tile 32 (wave-split 16+16) x j-tile 16.
// Ws slice lives in LDS (fragment-major, conflict-free) all 64 steps; c and mask in
// registers. h exchange + barrier via per-access agent-scope atomics (sc-bit ops,
// no cache-wide fences). Batch b-groups are independent: 32-WG barrier per group.
template <typename PIT>
__global__ __launch_bounds__(128)
void k_recur(const bf16_t* __restrict__ Wsb, const float* __restrict__ bs,
             const PIT* __restrict__ pi, const float* __restrict__ mask,
             bf16_t* __restrict__ Hs, unsigned* __restrict__ ctr) {
  extern __shared__ __align__(16) char smem[];
  bf16_t* Wl = (bf16_t*)smem;              // [5][16][64 lanes][8] fragment-major
  const int tid = threadIdx.x;
  const int l = tid & 63;
  const int w = tid >> 6;                  // wave: b-half
  const int l15 = l & 15, lq = l >> 4;
  const int bq = blockIdx.x, jq = blockIdx.y;
  const int b0 = bq * 32, j0 = jq * 16;
  const int j = j0 + l15;
  const int brow = b0 + w * 16;            // this wave's 16-row block base
  unsigned* myctr = ctr + bq * 64;         // 256B apart per group

  union U8 { unsigned long long q[2]; bf16x8 v; };
  union CV { bf16_t b; unsigned short u; };

  // one-time: build fragment-major Wl. slot s = g*16+kk; each wave does 40 slots.
  for (int s = w * 40; s < w * 40 + 40; ++s) {
    int g = s >> 4, kk = s & 15;
    bf16x8 frag = *(const bf16x8*)(Wsb + (size_t)(g * HH + j0 + l15) * HH + kk * 32 + lq * 8);
    *(bf16x8*)(Wl + (size_t)s * 512 + l * 8) = frag;
  }
  __syncthreads();

  float bsr[5];
#pragma unroll
  for (int g = 0; g < 5; ++g) bsr[g] = bs[g * HH + j];
  float mreg[4], creg[4] = {0.f, 0.f, 0.f, 0.f};
#pragma unroll
  for (int r = 0; r < 4; ++r)
    mreg[r] = mask[(size_t)(brow + lq * 4 + r) * HH + j];

  for (int t = 0; t < TT; ++t) {
    // wait for step t's h to be published (all 32 WGs of this b-group)
    if (t > 0) {
      if (tid == 0) {
        unsigned tgt = 32u * (unsigned)t;
        while (__hip_atomic_load(myctr, __ATOMIC_RELAXED, __HIP_MEMORY_SCOPE_AGENT) < tgt)
          __builtin_amdgcn_s_sleep(1);
      }
      __syncthreads();
    }

    // A-fragments: h rows direct to registers via agent-scope loads (bypass stale L2)
    const bf16_t* hsrc = Hs + (size_t)t * BB * HH + (size_t)(brow + l15) * HH;
    U8 au[16];
#pragma unroll
    for (int kk = 0; kk < 16; ++kk) {
      unsigned long long* p = (unsigned long long*)(hsrc + kk * 32 + lq * 8);
      au[kk].q[0] = __hip_atomic_load(p, __ATOMIC_RELAXED, __HIP_MEMORY_SCOPE_AGENT);
      au[kk].q[1] = __hip_atomic_load(p + 1, __ATOMIC_RELAXED, __HIP_MEMORY_SCOPE_AGENT);
    }

    // pi loads (normal; latency hides under the MFMA phase)
    const PIT* pit = pi + (size_t)t * BB * SIXH;
    float pv[4][6];
#pragma unroll
    for (int r = 0; r < 4; ++r) {
      const PIT* prow = pit + (size_t)(brow + lq * 4 + r) * SIXH + j;
#pragma unroll
      for (int g = 0; g < 6; ++g) pv[r][g] = (float)prow[g * HH];
    }

    // 5-gate GEMM: B-frags from fragment-major Wl (conflict-free lane-consecutive)
    f32x4 acc[5] = {};
#pragma unroll
    for (int kk = 0; kk < 16; ++kk) {
      bf16x8 a = au[kk].v;
#pragma unroll
      for (int g = 0; g < 5; ++g) {
        bf16x8 bb = *(const bf16x8*)(Wl + (size_t)(g * 16 + kk) * 512 + l * 8);
        acc[g] = mfma16(a, bb, acc[g]);
      }
    }

    // fused gates / state / highway / dropout; publish h via agent-scope stores
    bf16_t* hnext = Hs + (size_t)(t + 1) * BB * HH;
#pragma unroll
    for (int r = 0; r < 4; ++r) {
      int b = brow + lq * 4 + r;
      float ig = fsig(pv[r][0] + acc[0][r] + bsr[0]);
      float fg = fsig(pv[r][1] + acc[1][r] + bsr[1]);
      float mi = ftanh_(pv[r][2] + acc[2][r] + bsr[2]);
      float og = fsig(pv[r][3] + acc[3][r] + bsr[3]);
      float hg = fsig(pv[r][4] + acc[4][r] + bsr[4]);
      float cn = ig * mi + fg * creg[r];
      creg[r] = cn;
      float o = og * ftanh_(cn);
      o = hg * o + (1.f - hg) * pv[r][5];
      o *= mreg[r];
      CV cv; cv.b = (bf16_t)o;
      __hip_atomic_store((unsigned short*)(hnext + (size_t)b * HH + j), cv.u,
                         __ATOMIC_RELAXED, __HIP_MEMORY_SCOPE_AGENT);
    }

    // arrive: syncthreads drains vmcnt (stores at coherence point), then count
    __syncthreads();
    if (tid == 0)
      __hip_atomic_fetch_add(myctr, 1u, __ATOMIC_RELAXED, __HIP_MEMORY_SCOPE_AGENT);
  }
}

// ---------------- launcher ----------------
extern "C" void kernel_launch(void* const* d_in, const int* in_sizes, int n_in,
                              void* d_out, int out_size, void* d_ws, size_t ws_size,
                              hipStream_t stream) {
  const float* x    = (const float*)d_in[0];
  const int*   lab  = (const int*)d_in[1];
  const float* emb  = (const float*)d_in[2];
  const float* Wi   = (const float*)d_in[3];
  const float* bi   = (const float*)d_in[4];
  const float* Ws   = (const float*)d_in[5];
  const float* bs   = (const float*)d_in[6];
  const float* Wo   = (const float*)d_in[7];
  const float* bo   = (const float*)d_in[8];
  const float* mask = (const float*)d_in[9];
  float* out = (float*)d_out;

  char* w = (char*)d_ws;
  size_t off = 0;
  auto take = [&](size_t bytes) {
    void* p = w + off;
    off += (bytes + 255) & ~(size_t)255;
    return p;
  };

  bf16_t*   TI   = (bf16_t*)take((size_t)MROWS * KIN * 2);
  bf16_t*   Wib  = (bf16_t*)take((size_t)SIXH * KIN * 2);
  bf16_t*   Wsb  = (bf16_t*)take((size_t)FIVEH * HH * 2);
  bf16_t*   Wob  = (bf16_t*)take((size_t)256 * HH * 2);
  bf16_t*   Hs   = (bf16_t*)take((size_t)(TT + 1) * BB * HH * 2);  // slot 0 = h0 = 0
  unsigned* ctrs = (unsigned*)take(8 * 64 * sizeof(unsigned));
  void* piPtr = w + off;
  size_t avail = (ws_size > off) ? (ws_size - off) : 0;

  bool pifp32 = avail >= (size_t)MROWS * SIXH * 4;
  bool pibf16 = !pifp32 && avail >= (size_t)MROWS * SIXH * 2;
  if (!pifp32 && !pibf16) {
    hipMemsetAsync(d_out, 0, (size_t)out_size * 4, stream);  // diagnostic: ws too small
    return;
  }

  // weight conversions + input gather/concat + state init
  k_f2b<<<dim3(1024), dim3(256), 0, stream>>>(Wi, Wib, SIXH * KIN);
  k_f2b<<<dim3(512), dim3(256), 0, stream>>>(Ws, Wsb, FIVEH * HH);
  k_wopad<<<dim3(512), dim3(256), 0, stream>>>(Wo, Wob);
  k_gather<<<dim3(MROWS), dim3(256), 0, stream>>>(x, lab, emb, TI);
  hipMemsetAsync(Hs, 0, (size_t)BB * HH * 2, stream);
  hipMemsetAsync(ctrs, 0, 8 * 64 * sizeof(unsigned), stream);

  dim3 rg(8, 32), rb(128);
  if (pifp32) {
    float* pi = (float*)piPtr;
    k_gemm<float><<<dim3(SIXH / 128, MROWS / 128), dim3(256), 0, stream>>>(
        TI, Wib, bi, pi, MROWS, SIXH, KIN, SIXH, SIXH);
    const float* piC = pi;
    hipFuncSetAttribute((const void*)k_recur<float>,
                        hipFuncAttributeMaxDynamicSharedMemorySize, RLDS);
    void* args[6] = {&Wsb, &bs, &piC, &mask, &Hs, &ctrs};
    hipError_t e = hipLaunchCooperativeKernel((void*)k_recur<float>, rg, rb, args,
                                              RLDS, stream);
    if (e != hipSuccess)
      k_recur<float><<<rg, rb, RLDS, stream>>>(Wsb, bs, piC, mask, Hs, ctrs);
  } else {
    bf16_t* pi = (bf16_t*)piPtr;
    k_gemm<bf16_t><<<dim3(SIXH / 128, MROWS / 128), dim3(256), 0, stream>>>(
        TI, Wib, bi, pi, MROWS, SIXH, KIN, SIXH, SIXH);
    const bf16_t* piC = pi;
    hipFuncSetAttribute((const void*)k_recur<bf16_t>,
                        hipFuncAttributeMaxDynamicSharedMemorySize, RLDS);
    void* args[6] = {&Wsb, &bs, &piC, &mask, &Hs, &ctrs};
    hipError_t e = hipLaunchCooperativeKernel((void*)k_recur<bf16_t>, rg, rb, args,
                                              RLDS, stream);
    if (e != hipSuccess)
      k_recur<bf16_t><<<rg, rb, RLDS, stream>>>(Wsb, bs, piC, mask, Hs, ctrs);
  }

  // batched output projection: pred = h @ Wo^T + bo  (Wo zero-padded to 256 rows)
  k_gemm<float><<<dim3(2, MROWS / 128), dim3(256), 0, stream>>>(
      Hs + (size_t)BB * HH, Wob, bo, out, MROWS, 256, HH, NC, NC);
}